// Round 1
// baseline (245.878 us; speedup 1.0000x reference)
//
#include <hip/hip_runtime.h>

// ROIAlign: features (B=4, C=64, H=38, W=38) fp32, rois (B=4, Nb=2904, 4) fp32
// out: (N=11616, C=64, 7, 7) fp32
#define OUTSZ 7
#define PP    (OUTSZ * OUTSZ)   // 49 sample positions per ROI
#define NCH   64
#define FH    38
#define FW    38
#define NB    2904
#define HWSZ  (FH * FW)         // 1444
#define CHW   (NCH * HWSZ)      // 92416 per batch
#define ROI_ELEMS (NCH * PP)    // 3136 floats per ROI
#define ROI_VEC4  (ROI_ELEMS / 4) // 784

__global__ __launch_bounds__(256) void roi_align_kernel(
    const float* __restrict__ feat,
    const float* __restrict__ rois,
    float* __restrict__ out)
{
    __shared__ float s_w[PP][4];
    __shared__ int   s_off[PP][4];

    const int n   = blockIdx.x;      // roi index 0..11615
    const int b   = n / NB;          // batch index (compile-time magic div)
    const int tid = threadIdx.x;

    if (tid < PP) {
        const float x1 = rois[n * 4 + 0];
        const float y1 = rois[n * 4 + 1];
        const float x2 = rois[n * 4 + 2];
        const float y2 = rois[n * 4 + 3];
        const float w = fmaxf(x2 - x1, 1.0f);
        const float h = fmaxf(y2 - y1, 1.0f);
        const int i = tid / OUTSZ;   // row -> y
        const int j = tid % OUTSZ;   // col -> x
        const float x = x1 + ((float)j * (1.0f / 6.0f)) * w;
        const float y = y1 + ((float)i * (1.0f / 6.0f)) * h;
        const float x0f = floorf(x);
        const float y0f = floorf(y);
        const int x0 = (int)x0f;
        const int y0 = (int)y0f;
        const float fx = x - x0f;    // in [0,1)
        const float fy = y - y0f;
        const float wx0 = 1.0f - fx, wx1 = fx;
        const float wy0 = 1.0f - fy, wy1 = fy;
        // validity (zero padding outside [0, W-1]/[0, H-1])
        const bool vx0 = (x0 >= 0) && (x0 <= FW - 1);
        const bool vx1 = (x0 + 1 >= 0) && (x0 + 1 <= FW - 1);
        const bool vy0 = (y0 >= 0) && (y0 <= FH - 1);
        const bool vy1 = (y0 + 1 >= 0) && (y0 + 1 <= FH - 1);
        const int xi0 = min(max(x0, 0), FW - 1);
        const int xi1 = min(max(x0 + 1, 0), FW - 1);
        const int yi0 = min(max(y0, 0), FH - 1);
        const int yi1 = min(max(y0 + 1, 0), FH - 1);
        s_w[tid][0] = (vx0 && vy0) ? wx0 * wy0 : 0.0f;
        s_w[tid][1] = (vx1 && vy0) ? wx1 * wy0 : 0.0f;
        s_w[tid][2] = (vx0 && vy1) ? wx0 * wy1 : 0.0f;
        s_w[tid][3] = (vx1 && vy1) ? wx1 * wy1 : 0.0f;
        s_off[tid][0] = yi0 * FW + xi0;
        s_off[tid][1] = yi0 * FW + xi1;
        s_off[tid][2] = yi1 * FW + xi0;
        s_off[tid][3] = yi1 * FW + xi1;
    }
    __syncthreads();

    const float* __restrict__ fb = feat + (size_t)b * CHW;
    float* __restrict__ ob = out + (size_t)n * ROI_ELEMS;

    // 784 float4 stores per ROI across 256 threads
    #pragma unroll
    for (int it = 0; it < 4; ++it) {
        const int v = tid + it * 256;
        if (v < ROI_VEC4) {
            const int e = v * 4;
            float r[4];
            #pragma unroll
            for (int k = 0; k < 4; ++k) {
                const int ek = e + k;
                const int c = ek / PP;           // magic-mul div by 49
                const int p = ek - c * PP;
                const float* fc = fb + c * HWSZ;
                r[k] = s_w[p][0] * fc[s_off[p][0]]
                     + s_w[p][1] * fc[s_off[p][1]]
                     + s_w[p][2] * fc[s_off[p][2]]
                     + s_w[p][3] * fc[s_off[p][3]];
            }
            float4 r4 = make_float4(r[0], r[1], r[2], r[3]);
            *reinterpret_cast<float4*>(ob + e) = r4;
        }
    }
}

extern "C" void kernel_launch(void* const* d_in, const int* in_sizes, int n_in,
                              void* d_out, int out_size, void* d_ws, size_t ws_size,
                              hipStream_t stream) {
    const float* feat = (const float*)d_in[0];   // 4*64*38*38
    const float* rois = (const float*)d_in[1];   // 4*2904*4
    float* out = (float*)d_out;                  // 11616*64*7*7

    const int n_rois = 4 * NB;                   // 11616
    roi_align_kernel<<<n_rois, 256, 0, stream>>>(feat, rois, out);
}

// Round 2
// 163.844 us; speedup vs baseline: 1.5007x; 1.5007x over previous
//
#include <hip/hip_runtime.h>

// ROIAlign: features (B=4, C=64, H=38, W=38) fp32, rois (B=4, Nb=2904, 4) fp32
// out: (N=11616, C=64, 7, 7) fp32
// Strategy: pre-transpose features to HWC so each bilinear corner read is
// 64 consecutive floats (coalesced); LDS tile transposes back to CHW for
// coalesced output stores.
#define OUTSZ 7
#define PP    (OUTSZ * OUTSZ)   // 49 sample positions per ROI
#define NCH   64
#define FH    38
#define FW    38
#define NB    2904
#define HWSZ  (FH * FW)         // 1444
#define CHW   (NCH * HWSZ)      // 92416 per batch
#define ROI_ELEMS (NCH * PP)    // 3136 floats per ROI
#define TPAD  65                // LDS tile row stride (conflict-free both phases)

// --- Kernel A: CHW -> HWC transpose of features (1.48 MB total) ---
__global__ __launch_bounds__(256) void transpose_kernel(
    const float* __restrict__ feat,   // (4,64,38,38)
    float* __restrict__ fhwc)         // (4,38,38,64)
{
    const int o = blockIdx.x * 256 + threadIdx.x;  // 0 .. 4*1444*64-1
    const int c   = o & (NCH - 1);
    const int pos = o >> 6;            // b*1444 + yx
    const int b   = pos / HWSZ;
    const int yx  = pos - b * HWSZ;
    fhwc[o] = feat[b * CHW + c * HWSZ + yx];
}

// --- Kernel B: one block (256 thr = 4 waves) per ROI ---
__global__ __launch_bounds__(256) void roi_align_kernel(
    const float* __restrict__ fhwc,
    const float* __restrict__ rois,
    float* __restrict__ out)
{
    __shared__ float s_w[PP][4];
    __shared__ int   s_off[PP][4];     // element offsets into batch-HWC plane
    __shared__ float s_t[PP][TPAD];    // [p][c] result tile

    const int n   = blockIdx.x;        // roi index 0..11615
    const int b   = n / NB;
    const int tid = threadIdx.x;

    if (tid < PP) {
        const float x1 = rois[n * 4 + 0];
        const float y1 = rois[n * 4 + 1];
        const float x2 = rois[n * 4 + 2];
        const float y2 = rois[n * 4 + 3];
        const float w = fmaxf(x2 - x1, 1.0f);
        const float h = fmaxf(y2 - y1, 1.0f);
        const int i = tid / OUTSZ;     // row -> y
        const int j = tid % OUTSZ;     // col -> x
        const float x = x1 + ((float)j * (1.0f / 6.0f)) * w;
        const float y = y1 + ((float)i * (1.0f / 6.0f)) * h;
        const float x0f = floorf(x);
        const float y0f = floorf(y);
        const int x0 = (int)x0f;
        const int y0 = (int)y0f;
        const float fx = x - x0f;
        const float fy = y - y0f;
        const float wx0 = 1.0f - fx, wx1 = fx;
        const float wy0 = 1.0f - fy, wy1 = fy;
        const bool vx0 = (x0 >= 0) && (x0 <= FW - 1);
        const bool vx1 = (x0 + 1 >= 0) && (x0 + 1 <= FW - 1);
        const bool vy0 = (y0 >= 0) && (y0 <= FH - 1);
        const bool vy1 = (y0 + 1 >= 0) && (y0 + 1 <= FH - 1);
        const int xi0 = min(max(x0, 0), FW - 1);
        const int xi1 = min(max(x0 + 1, 0), FW - 1);
        const int yi0 = min(max(y0, 0), FH - 1);
        const int yi1 = min(max(y0 + 1, 0), FH - 1);
        s_w[tid][0] = (vx0 && vy0) ? wx0 * wy0 : 0.0f;
        s_w[tid][1] = (vx1 && vy0) ? wx1 * wy0 : 0.0f;
        s_w[tid][2] = (vx0 && vy1) ? wx0 * wy1 : 0.0f;
        s_w[tid][3] = (vx1 && vy1) ? wx1 * wy1 : 0.0f;
        s_off[tid][0] = (yi0 * FW + xi0) * NCH;
        s_off[tid][1] = (yi0 * FW + xi1) * NCH;
        s_off[tid][2] = (yi1 * FW + xi0) * NCH;
        s_off[tid][3] = (yi1 * FW + xi1) * NCH;
    }
    __syncthreads();

    const float* __restrict__ fb = fhwc + (size_t)b * CHW;

    // Phase 2: wave per sample point, lane = channel. All loads 256B coalesced.
    const int wave = tid >> 6;
    const int lane = tid & 63;
    for (int p = wave; p < PP; p += 4) {
        const float w0 = s_w[p][0], w1 = s_w[p][1], w2 = s_w[p][2], w3 = s_w[p][3];
        const int   o0 = s_off[p][0], o1 = s_off[p][1], o2 = s_off[p][2], o3 = s_off[p][3];
        float acc = fb[o0 + lane] * w0;
        acc += fb[o1 + lane] * w1;
        acc += fb[o2 + lane] * w2;
        acc += fb[o3 + lane] * w3;
        s_t[p][lane] = acc;            // bank stride 1 across lanes: conflict-free
    }
    __syncthreads();

    // Phase 3: coalesced CHW-order store. e = c*49 + p; consecutive lanes ->
    // consecutive p -> LDS addr stride TPAD=65 -> bank stride 1: conflict-free.
    float* __restrict__ ob = out + (size_t)n * ROI_ELEMS;
    #pragma unroll
    for (int it = 0; it < 13; ++it) {
        const int e = tid + it * 256;
        if (e < ROI_ELEMS) {
            const int c = e / PP;       // magic-mul
            const int p = e - c * PP;
            ob[e] = s_t[p][c];
        }
    }
}

extern "C" void kernel_launch(void* const* d_in, const int* in_sizes, int n_in,
                              void* d_out, int out_size, void* d_ws, size_t ws_size,
                              hipStream_t stream) {
    const float* feat = (const float*)d_in[0];   // 4*64*38*38
    const float* rois = (const float*)d_in[1];   // 4*2904*4
    float* out  = (float*)d_out;                 // 11616*64*7*7
    float* fhwc = (float*)d_ws;                  // 4*38*38*64 = 1.48 MB scratch

    transpose_kernel<<<(4 * HWSZ * NCH) / 256, 256, 0, stream>>>(feat, fhwc);
    roi_align_kernel<<<4 * NB, 256, 0, stream>>>(fhwc, rois, out);
}

// Round 3
// 155.040 us; speedup vs baseline: 1.5859x; 1.0568x over previous
//
#include <hip/hip_runtime.h>

// ROIAlign: features (B=4, C=64, H=38, W=38) fp32, rois (B=4, Nb=2904, 4) fp32
// out: (N=11616, C=64, 7, 7) fp32
// Strategy: tiled CHW->HWC transpose (coalesced both sides), then per-ROI
// block: 16 lanes x float4 per sample point -> dwordx4 gathers; LDS tile
// transposes back to CHW for coalesced output stores.
#define OUTSZ 7
#define PP    (OUTSZ * OUTSZ)   // 49 sample positions per ROI
#define NCH   64
#define FH    38
#define FW    38
#define NB    2904
#define HWSZ  (FH * FW)         // 1444
#define CHW   (NCH * HWSZ)      // 92416 per batch
#define ROI_ELEMS (NCH * PP)    // 3136 floats per ROI
#define TPAD  65                // LDS result tile row stride

// --- Kernel A: CHW -> HWC transpose via 64x64 LDS tile, coalesced both ways ---
__global__ __launch_bounds__(256) void transpose_kernel(
    const float* __restrict__ feat,   // (4,64,38,38)
    float* __restrict__ fhwc)         // (4,38,38,64)
{
    __shared__ float s[64][65];
    const int b   = blockIdx.y;
    const int yx0 = blockIdx.x * 64;
    const int tid  = threadIdx.x;
    const int lane = tid & 63;
    const int grp  = tid >> 6;        // 0..3

    const int yx = yx0 + lane;
    if (yx < HWSZ) {
        #pragma unroll
        for (int i = 0; i < 16; ++i) {
            const int c = grp * 16 + i;
            s[c][lane] = feat[b * CHW + c * HWSZ + yx];   // coalesced along yx
        }
    }
    __syncthreads();
    #pragma unroll
    for (int i = 0; i < 16; ++i) {
        const int yxl = grp * 16 + i;
        const int yxg = yx0 + yxl;
        if (yxg < HWSZ) {
            fhwc[b * CHW + yxg * NCH + lane] = s[lane][yxl];  // coalesced along c
        }
    }
}

// --- Kernel B: one block (256 thr = 4 waves) per ROI ---
__global__ __launch_bounds__(256) void roi_align_kernel(
    const float* __restrict__ fhwc,
    const float* __restrict__ rois,
    float* __restrict__ out)
{
    __shared__ float s_w[PP][4];
    __shared__ int   s_off[PP][4];     // element offsets into batch-HWC plane
    __shared__ float s_t[PP][TPAD];    // [p][c] result tile

    const int n   = blockIdx.x;        // roi index 0..11615
    const int b   = n / NB;
    const int tid = threadIdx.x;

    if (tid < PP) {
        const float x1 = rois[n * 4 + 0];
        const float y1 = rois[n * 4 + 1];
        const float x2 = rois[n * 4 + 2];
        const float y2 = rois[n * 4 + 3];
        const float w = fmaxf(x2 - x1, 1.0f);
        const float h = fmaxf(y2 - y1, 1.0f);
        const int i = tid / OUTSZ;     // row -> y
        const int j = tid % OUTSZ;     // col -> x
        const float x = x1 + ((float)j * (1.0f / 6.0f)) * w;
        const float y = y1 + ((float)i * (1.0f / 6.0f)) * h;
        const float x0f = floorf(x);
        const float y0f = floorf(y);
        const int x0 = (int)x0f;
        const int y0 = (int)y0f;
        const float fx = x - x0f;
        const float fy = y - y0f;
        const float wx0 = 1.0f - fx, wx1 = fx;
        const float wy0 = 1.0f - fy, wy1 = fy;
        const bool vx0 = (x0 >= 0) && (x0 <= FW - 1);
        const bool vx1 = (x0 + 1 >= 0) && (x0 + 1 <= FW - 1);
        const bool vy0 = (y0 >= 0) && (y0 <= FH - 1);
        const bool vy1 = (y0 + 1 >= 0) && (y0 + 1 <= FH - 1);
        const int xi0 = min(max(x0, 0), FW - 1);
        const int xi1 = min(max(x0 + 1, 0), FW - 1);
        const int yi0 = min(max(y0, 0), FH - 1);
        const int yi1 = min(max(y0 + 1, 0), FH - 1);
        s_w[tid][0] = (vx0 && vy0) ? wx0 * wy0 : 0.0f;
        s_w[tid][1] = (vx1 && vy0) ? wx1 * wy0 : 0.0f;
        s_w[tid][2] = (vx0 && vy1) ? wx0 * wy1 : 0.0f;
        s_w[tid][3] = (vx1 && vy1) ? wx1 * wy1 : 0.0f;
        s_off[tid][0] = (yi0 * FW + xi0) * NCH;
        s_off[tid][1] = (yi0 * FW + xi1) * NCH;
        s_off[tid][2] = (yi1 * FW + xi0) * NCH;
        s_off[tid][3] = (yi1 * FW + xi1) * NCH;
    }
    __syncthreads();

    const float* __restrict__ fb = fhwc + (size_t)b * CHW;

    // Phase 2: 16 lanes per sample point, each lane owns 4 consecutive channels.
    // All gathers are global_load_dwordx4 (16 B/lane, 256 B per point, aligned).
    const int sub = tid & 15;          // channel quad index 0..15
    const int pg  = tid >> 4;          // point slot 0..15
    #pragma unroll
    for (int pass = 0; pass < 4; ++pass) {
        const int p = pass * 16 + pg;  // 0..63
        if (p < PP) {
            const float w0 = s_w[p][0], w1 = s_w[p][1], w2 = s_w[p][2], w3 = s_w[p][3];
            const int cq = sub * 4;
            const float4 v0 = *reinterpret_cast<const float4*>(fb + s_off[p][0] + cq);
            const float4 v1 = *reinterpret_cast<const float4*>(fb + s_off[p][1] + cq);
            const float4 v2 = *reinterpret_cast<const float4*>(fb + s_off[p][2] + cq);
            const float4 v3 = *reinterpret_cast<const float4*>(fb + s_off[p][3] + cq);
            // scalar LDS writes: bank = (p + 4*sub + j) mod 32 -> exactly 2-way (free)
            s_t[p][cq + 0] = v0.x * w0 + v1.x * w1 + v2.x * w2 + v3.x * w3;
            s_t[p][cq + 1] = v0.y * w0 + v1.y * w1 + v2.y * w2 + v3.y * w3;
            s_t[p][cq + 2] = v0.z * w0 + v1.z * w1 + v2.z * w2 + v3.z * w3;
            s_t[p][cq + 3] = v0.w * w0 + v1.w * w1 + v2.w * w2 + v3.w * w3;
        }
    }
    __syncthreads();

    // Phase 3: coalesced CHW-order store. e = c*49 + p; consecutive lanes ->
    // consecutive p -> LDS addr stride TPAD=65 -> bank stride 1: conflict-free.
    float* __restrict__ ob = out + (size_t)n * ROI_ELEMS;
    #pragma unroll
    for (int it = 0; it < 13; ++it) {
        const int e = tid + it * 256;
        if (e < ROI_ELEMS) {
            const int c = e / PP;       // magic-mul
            const int p = e - c * PP;
            ob[e] = s_t[p][c];
        }
    }
}

extern "C" void kernel_launch(void* const* d_in, const int* in_sizes, int n_in,
                              void* d_out, int out_size, void* d_ws, size_t ws_size,
                              hipStream_t stream) {
    const float* feat = (const float*)d_in[0];   // 4*64*38*38
    const float* rois = (const float*)d_in[1];   // 4*2904*4
    float* out  = (float*)d_out;                 // 11616*64*7*7
    float* fhwc = (float*)d_ws;                  // 4*38*38*64 = 1.48 MB scratch

    dim3 tg((HWSZ + 63) / 64, 4);
    transpose_kernel<<<tg, 256, 0, stream>>>(feat, fhwc);
    roi_align_kernel<<<4 * NB, 256, 0, stream>>>(fhwc, rois, out);
}

// Round 4
// 154.270 us; speedup vs baseline: 1.5938x; 1.0050x over previous
//
#include <hip/hip_runtime.h>
#include <hip/hip_fp16.h>

// ROIAlign: features (B=4, C=64, H=38, W=38) fp32, rois (B=4, 2904, 4) fp32
// out: (N=11616, C=64, 7, 7) fp32
// R4: HWC scratch copy stored as fp16 -> each bilinear corner read is 128 B
// (2 cache lines) instead of 256 B (4 lines); gathers are L1-line-bound.
#define OUTSZ 7
#define PP    (OUTSZ * OUTSZ)   // 49 sample positions per ROI
#define NCH   64
#define FH    38
#define FW    38
#define NB    2904
#define HWSZ  (FH * FW)         // 1444
#define CHW   (NCH * HWSZ)      // 92416 per batch
#define ROI_ELEMS (NCH * PP)    // 3136 floats per ROI
#define TPAD  65                // LDS result tile row stride (conflict-free)

typedef __attribute__((ext_vector_type(4))) _Float16 half4;

// --- Kernel A: CHW fp32 -> HWC fp16 transpose via LDS tile (32 pos x 64 ch) ---
__global__ __launch_bounds__(256) void transpose_kernel(
    const float* __restrict__ feat,   // (4,64,38,38) fp32
    _Float16* __restrict__ fhwc)      // (4,38,38,64) fp16
{
    __shared__ float s[64][33];
    const int b   = blockIdx.y;
    const int yx0 = blockIdx.x * 32;
    const int tid  = threadIdx.x;
    const int lane = tid & 31;        // position within tile (read) / channel pair base (write)
    const int grp  = tid >> 5;        // 0..7

    const int yx = yx0 + lane;
    if (yx < HWSZ) {
        #pragma unroll
        for (int i = 0; i < 8; ++i) {
            const int c = grp * 8 + i;
            s[c][lane] = feat[b * CHW + c * HWSZ + yx];   // coalesced along yx
        }
    }
    __syncthreads();
    // write: 256 threads cover 32 positions x 64 channels in 8 iters
    #pragma unroll
    for (int i = 0; i < 8; ++i) {
        const int item = i * 256 + tid;        // 0..2047
        const int c   = item & 63;
        const int yxl = item >> 6;             // 0..31
        const int yxg = yx0 + yxl;
        if (yxg < HWSZ) {
            fhwc[b * CHW + yxg * NCH + c] = (_Float16)s[c][yxl];  // coalesced
        }
    }
}

// --- Kernel B: one block (256 thr = 4 waves) per ROI ---
__global__ __launch_bounds__(256) void roi_align_kernel(
    const _Float16* __restrict__ fhwc,
    const float* __restrict__ rois,
    float* __restrict__ out)
{
    __shared__ float s_w[PP][4];
    __shared__ int   s_off[PP][4];     // element offsets into batch-HWC plane
    __shared__ float s_t[PP][TPAD];    // [p][c] result tile

    const int n   = blockIdx.x;        // roi index 0..11615
    const int b   = n / NB;
    const int tid = threadIdx.x;

    if (tid < PP) {
        const float x1 = rois[n * 4 + 0];
        const float y1 = rois[n * 4 + 1];
        const float x2 = rois[n * 4 + 2];
        const float y2 = rois[n * 4 + 3];
        const float w = fmaxf(x2 - x1, 1.0f);
        const float h = fmaxf(y2 - y1, 1.0f);
        const int i = tid / OUTSZ;     // row -> y
        const int j = tid % OUTSZ;     // col -> x
        const float x = x1 + ((float)j * (1.0f / 6.0f)) * w;
        const float y = y1 + ((float)i * (1.0f / 6.0f)) * h;
        const float x0f = floorf(x);
        const float y0f = floorf(y);
        const int x0 = (int)x0f;
        const int y0 = (int)y0f;
        const float fx = x - x0f;
        const float fy = y - y0f;
        const float wx0 = 1.0f - fx, wx1 = fx;
        const float wy0 = 1.0f - fy, wy1 = fy;
        const bool vx0 = (x0 >= 0) && (x0 <= FW - 1);
        const bool vx1 = (x0 + 1 >= 0) && (x0 + 1 <= FW - 1);
        const bool vy0 = (y0 >= 0) && (y0 <= FH - 1);
        const bool vy1 = (y0 + 1 >= 0) && (y0 + 1 <= FH - 1);
        const int xi0 = min(max(x0, 0), FW - 1);
        const int xi1 = min(max(x0 + 1, 0), FW - 1);
        const int yi0 = min(max(y0, 0), FH - 1);
        const int yi1 = min(max(y0 + 1, 0), FH - 1);
        s_w[tid][0] = (vx0 && vy0) ? wx0 * wy0 : 0.0f;
        s_w[tid][1] = (vx1 && vy0) ? wx1 * wy0 : 0.0f;
        s_w[tid][2] = (vx0 && vy1) ? wx0 * wy1 : 0.0f;
        s_w[tid][3] = (vx1 && vy1) ? wx1 * wy1 : 0.0f;
        s_off[tid][0] = (yi0 * FW + xi0) * NCH;
        s_off[tid][1] = (yi0 * FW + xi1) * NCH;
        s_off[tid][2] = (yi1 * FW + xi0) * NCH;
        s_off[tid][3] = (yi1 * FW + xi1) * NCH;
    }
    __syncthreads();

    const _Float16* __restrict__ fb = fhwc + (size_t)b * CHW;

    // Phase 2: 16 lanes per sample point, each lane owns 4 consecutive channels.
    // fp16x4 loads: 8 B/lane, 128 B (2 lines) per corner per point.
    const int sub = tid & 15;          // channel quad index 0..15
    const int pg  = tid >> 4;          // point slot 0..15
    #pragma unroll
    for (int pass = 0; pass < 4; ++pass) {
        const int p = pass * 16 + pg;  // 0..63
        if (p < PP) {
            const float w0 = s_w[p][0], w1 = s_w[p][1], w2 = s_w[p][2], w3 = s_w[p][3];
            const int cq = sub * 4;
            const half4 v0 = *reinterpret_cast<const half4*>(fb + s_off[p][0] + cq);
            const half4 v1 = *reinterpret_cast<const half4*>(fb + s_off[p][1] + cq);
            const half4 v2 = *reinterpret_cast<const half4*>(fb + s_off[p][2] + cq);
            const half4 v3 = *reinterpret_cast<const half4*>(fb + s_off[p][3] + cq);
            // scalar LDS writes: bank = (p + 4*sub + j) mod 32 -> exactly 2-way (free)
            s_t[p][cq + 0] = (float)v0[0] * w0 + (float)v1[0] * w1 + (float)v2[0] * w2 + (float)v3[0] * w3;
            s_t[p][cq + 1] = (float)v0[1] * w0 + (float)v1[1] * w1 + (float)v2[1] * w2 + (float)v3[1] * w3;
            s_t[p][cq + 2] = (float)v0[2] * w0 + (float)v1[2] * w1 + (float)v2[2] * w2 + (float)v3[2] * w3;
            s_t[p][cq + 3] = (float)v0[3] * w0 + (float)v1[3] * w1 + (float)v2[3] * w2 + (float)v3[3] * w3;
        }
    }
    __syncthreads();

    // Phase 3: coalesced CHW-order store. e = c*49 + p; consecutive lanes ->
    // consecutive p -> LDS addr stride TPAD=65 -> bank stride 1: conflict-free.
    float* __restrict__ ob = out + (size_t)n * ROI_ELEMS;
    #pragma unroll
    for (int it = 0; it < 13; ++it) {
        const int e = tid + it * 256;
        if (e < ROI_ELEMS) {
            const int c = e / PP;       // magic-mul
            const int p = e - c * PP;
            ob[e] = s_t[p][c];
        }
    }
}

extern "C" void kernel_launch(void* const* d_in, const int* in_sizes, int n_in,
                              void* d_out, int out_size, void* d_ws, size_t ws_size,
                              hipStream_t stream) {
    const float* feat = (const float*)d_in[0];   // 4*64*38*38
    const float* rois = (const float*)d_in[1];   // 4*2904*4
    float* out  = (float*)d_out;                 // 11616*64*7*7
    _Float16* fhwc = (_Float16*)d_ws;            // 4*38*38*64 fp16 = 739 KB scratch

    dim3 tg((HWSZ + 31) / 32, 4);
    transpose_kernel<<<tg, 256, 0, stream>>>(feat, fhwc);
    roi_align_kernel<<<4 * NB, 256, 0, stream>>>(fhwc, rois, out);
}